// Round 5
// baseline (507.525 us; speedup 1.0000x reference)
//
#include <hip/hip_runtime.h>

// Shapes
// B=8, NF=64, FIN=192, FH=128, FOUT=64, LAT=512, P_TOTAL=61824
// dyn param offsets: w_in 0, b_in 24576, w_mid 24704, b_mid 41088,
//                    w_out 41216, b_out 49408, w_sk 49472, b_sk 61760

#define BATCH 8
#define PT 61824

typedef __attribute__((ext_vector_type(8))) short bf16x8;
typedef __attribute__((ext_vector_type(4))) float f32x4;

__device__ __forceinline__ float lrelu(float v) { return v > 0.f ? v : 0.2f * v; }

__device__ __forceinline__ short f2bf(float f) {
    union { float fv; unsigned u; } v; v.fv = f;
    return (short)((v.u + 0x7fffu + ((v.u >> 16) & 1u)) >> 16);  // RNE
}

// packed f32x2 -> bf16x2 (RNE), single instruction; no builtin on gfx950
__device__ __forceinline__ unsigned cvt_pk_bf16(float lo, float hi) {
    unsigned r;
    asm("v_cvt_pk_bf16_f32 %0, %1, %2" : "=v"(r) : "v"(lo), "v"(hi));
    return r;
}
// single f32 -> bf16 (RNE) in ONE instruction (low half of cvt_pk)
__device__ __forceinline__ short f2bf1(float f) {
    unsigned r;
    asm("v_cvt_pk_bf16_f32 %0, %1, %1" : "=v"(r) : "v"(f));
    return (short)r;
}

// ---------------------------------------------------------------------------
// Kernel 1: hypernetwork  dyn[b][p] = sum_k inj[b][k] * hyp_w[k][p] + hyp_b[p]
// 4-way K-split; grid 966 (~3.8/CU). Round 4: fp32 dyn written only for the
// bias ranges (the only fp32 consumers); weights go out as bf16 only.
// ---------------------------------------------------------------------------
__global__ __launch_bounds__(256) void hyper_kernel(
    const float* __restrict__ inj, const float* __restrict__ hw,
    const float* __restrict__ hb, float* __restrict__ dyn,
    short* __restrict__ dyn16)
{
    __shared__ float s_l[512 * 8];        // transposed: s_l[k*8 + b]
    __shared__ float s_part[3 * 8 * 64];  // partials from kq = 1..3
    int t = threadIdx.x;
    for (int i = t; i < 4096; i += 256) {
        int b = i >> 9, k = i & 511;
        s_l[k * 8 + b] = inj[i];
    }
    __syncthreads();
    int po = t & 63, kq = t >> 6;
    int p = blockIdx.x * 64 + po;         // PT = 966*64 exactly
    float acc[8];
#pragma unroll
    for (int b = 0; b < 8; ++b) acc[b] = 0.f;
    for (int k = kq * 128; k < kq * 128 + 128; ++k) {
        float w = hw[(size_t)k * PT + p];
        float4 a0 = *(const float4*)&s_l[k * 8];
        float4 a1 = *(const float4*)&s_l[k * 8 + 4];
        acc[0] += a0.x * w; acc[1] += a0.y * w; acc[2] += a0.z * w; acc[3] += a0.w * w;
        acc[4] += a1.x * w; acc[5] += a1.y * w; acc[6] += a1.z * w; acc[7] += a1.w * w;
    }
    if (kq > 0) {
#pragma unroll
        for (int b = 0; b < 8; ++b) s_part[((kq - 1) * 8 + b) * 64 + po] = acc[b];
    }
    __syncthreads();
    if (kq == 0) {
        float bias = hb[p];
        bool isb = (p >= 24576 && p < 24704) || (p >= 41088 && p < 41216)
                || (p >= 49408 && p < 49472) || (p >= 61760);
#pragma unroll
        for (int b = 0; b < 8; ++b) {
            float v = acc[b] + s_part[b * 64 + po] + s_part[(8 + b) * 64 + po]
                    + s_part[(16 + b) * 64 + po] + bias;
            if (isb) dyn[(size_t)b * PT + p] = v;
            dyn16[(size_t)b * PT + p] = f2bf1(v);
        }
    }
}

// ---------------------------------------------------------------------------
// Kernel 2: stem (MFMA version from round 0; ~12 us.)
// ---------------------------------------------------------------------------
__global__ __launch_bounds__(256) void stem_kernel(
    const float* __restrict__ x, const float* __restrict__ in_w,
    const float* __restrict__ in_b,
    const float* __restrict__ w0, const float* __restrict__ b0,
    const float* __restrict__ w1, const float* __restrict__ b1,
    float* __restrict__ out0)
{
    const int HW = 128 * 128;
    __shared__ float s_t0[64 * 68];      // fp32 t0 [c][px] stride 68
    __shared__ short s_vh[2 * 64 * 72];  // bf16 v then h, [px][k] stride 72
    __shared__ float s_x[192];
    short* s_v = s_vh;
    short* s_h = s_vh + 64 * 72;
    float* s_y = (float*)s_vh;           // fp32 d [c][px] stride 68 (aliases v/h)

    const int b = blockIdx.x >> 8;       // 256 tiles per sample
    const int tile = blockIdx.x & 255;
    const int pix0 = tile * 64;
    const int t = threadIdx.x;
    const int l = t & 63, w = t >> 6;
    const int lp = l & 15, lq = l >> 4;

    if (t < 192) s_x[t] = x[(size_t)b * 3 * HW + (t >> 6) * HW + pix0 + (t & 63)];
    __syncthreads();

    // ---- phase A: t0 = in_b + in_w * x (fp32), v = lrelu(t0) -> bf16 ----
    for (int j = t; j < 1024; j += 256) {
        int p = j & 63, cg = j >> 6;     // cg wave-uniform -> scalar weight loads
        float x0 = s_x[p], x1 = s_x[64 + p], x2 = s_x[128 + p];
        short pk[4];
#pragma unroll
        for (int cc = 0; cc < 4; ++cc) {
            int c = cg * 4 + cc;
            float v = in_b[c] + x0 * in_w[c * 3] + x1 * in_w[c * 3 + 1]
                    + x2 * in_w[c * 3 + 2];
            s_t0[c * 68 + p] = v;
            pk[cc] = f2bf1(lrelu(v));
        }
        *(short4*)&s_v[p * 72 + cg * 4] = make_short4(pk[0], pk[1], pk[2], pk[3]);
    }
    __syncthreads();

    const int o = w * 16 + lp;
    const f32x4 z4 = {0.f, 0.f, 0.f, 0.f};

    // weight rows as bf16 fragments (w0/w1 are tiny, L2-resident across blocks)
    bf16x8 wb0[2], wb1[2];
#pragma unroll
    for (int k = 0; k < 2; ++k) {
        bf16x8 p0, p1;
#pragma unroll
        for (int e = 0; e < 8; ++e) {
            p0[e] = f2bf1(w0[o * 64 + k * 32 + lq * 8 + e]);
            p1[e] = f2bf1(w1[o * 64 + k * 32 + lq * 8 + e]);
        }
        wb0[k] = p0; wb1[k] = p1;
    }

    // ---- phase B: h = lrelu(w0 * v + b0)  O=64, K=64 ----
    {
        float bi = b0[o];
        f32x4 acc[4];
#pragma unroll
        for (int mt = 0; mt < 4; ++mt) acc[mt] = z4;
#pragma unroll
        for (int k = 0; k < 2; ++k)
#pragma unroll
            for (int mt = 0; mt < 4; ++mt) {
                bf16x8 a = *(const bf16x8*)&s_v[(mt * 16 + lp) * 72 + k * 32 + lq * 8];
                acc[mt] = __builtin_amdgcn_mfma_f32_16x16x32_bf16(a, wb0[k], acc[mt], 0, 0, 0);
            }
#pragma unroll
        for (int mt = 0; mt < 4; ++mt)
#pragma unroll
            for (int r = 0; r < 4; ++r)
                s_h[(mt * 16 + lq * 4 + r) * 72 + o] = f2bf1(lrelu(acc[mt][r] + bi));
    }
    __syncthreads();

    // ---- phase C: d = 0.1 * (w1 * h + b1)  O=64, K=64 ----
    {
        float bi = b1[o];
        f32x4 acc[4];
#pragma unroll
        for (int mt = 0; mt < 4; ++mt) acc[mt] = z4;
#pragma unroll
        for (int k = 0; k < 2; ++k)
#pragma unroll
            for (int mt = 0; mt < 4; ++mt) {
                bf16x8 a = *(const bf16x8*)&s_h[(mt * 16 + lp) * 72 + k * 32 + lq * 8];
                acc[mt] = __builtin_amdgcn_mfma_f32_16x16x32_bf16(a, wb1[k], acc[mt], 0, 0, 0);
            }
        __syncthreads();  // all s_h reads complete before aliased s_y writes
#pragma unroll
        for (int mt = 0; mt < 4; ++mt) {
            f32x4 dv;
#pragma unroll
            for (int r = 0; r < 4; ++r) dv[r] = 0.1f * (acc[mt][r] + bi);
            *(f32x4*)&s_y[o * 68 + mt * 16 + lq * 4] = dv;
        }
    }
    __syncthreads();

    // ---- phase D: out = t0 + d, coalesced f32x4 stores ----
#pragma unroll
    for (int v = 0; v < 4; ++v) {
        int idx = v * 1024 + t * 4;
        int oo = idx >> 6, px = idx & 63;
        f32x4 t0v = *(const f32x4*)&s_t0[oo * 68 + px];
        f32x4 dv = *(const f32x4*)&s_y[oo * 68 + px];
        f32x4 ov = t0v + dv;
        *(f32x4*)&out0[((size_t)b * 64 + oo) * HW + pix0 + px] = ov;
    }
}

// ---------------------------------------------------------------------------
// Kernel 3: fused iteration via MFMA.
// Round 4: (a) 1-instr bf16 converts in epilogues (was 5-op software RNE,
// ~400 VALU/wave); (b) k-loops unrolled x2 so dyn16 weight loads pipeline
// ahead of their MFMAs; (c) bias + leak loads hoisted off the critical tail.
// ---------------------------------------------------------------------------
template<int MT>
__global__ __launch_bounds__(256, 4) void iter_kernel(
    const float* __restrict__ cur, const float* __restrict__ dynf,
    const short* __restrict__ dynb, const float* __restrict__ leak_p,
    float* __restrict__ y, int S, int sh)
{
    constexpr int PX = MT * 16;
    constexpr int SY = (MT == 4) ? 68 : 20;   // fp32 out stride (words)
    __shared__ short s_s[PX * 192];   // bf16 sobel [pix][192], XOR-swizzled
    __shared__ short s_h[PX * 128];   // bf16 h1/h2 [pix][128], XOR-swizzled
    float* s_y = (float*)s_s;         // fp32 d [o][px] (plain layout)

    const int HW = S * S;
    const int tilesPer = HW / PX;
    // XCD-chunked swizzle: chunk boundary == sample boundary at every S.
    const int nwg = BATCH * tilesPer;
    const int rb = (int)blockIdx.x;
    const int lb = (rb & 7) * (nwg >> 3) + (rb >> 3);
    const int b = lb / tilesPer;
    const int tile = lb - b * tilesPer;
    const int pix0 = tile * PX;
    const int t = threadIdx.x;
    const int l = t & 63, w = t >> 6;
    const int lp = l & 15, lq = l >> 4;
    const float* base = cur + (size_t)b * 64 * HW;
    const float lk = fminf(fmaxf(leak_p[0], 0.001f), 1000.f);  // hoisted off tail

    // ---- phase 0: sin_sobel via shuffles (fully unrolled, cvt_pk packing) ----
    {
        const int p = (MT == 4) ? (lp + 16 * w) : lp;
        const int rxw = (p & 7) << 2;         // dword-XOR for row p
        const int gpx = pix0 + p;
        const int row = gpx >> sh;
        const int x = gpx & (S - 1);
        const bool rm = (row > 0), rp = (row < S - 1);
        const bool le = (lp == 0) && (x > 0);
        const bool re = (lp == 15) && (x < S - 1);
        constexpr int iters = (MT == 4) ? 8 : 2;
        int* s32 = (int*)s_s;
#pragma unroll
        for (int i = 0; i < iters; ++i) {
            const int cp = (MT == 4) ? (lq + 4 * i) : (lq + 4 * w + 16 * i);
            float v0s[2], sxs[2], sys[2];
#pragma unroll
            for (int cc = 0; cc < 2; ++cc) {
                const int c = 2 * cp + cc;
                const float* ch = base + (size_t)c * HW + row * S;
                float vm = rm ? ch[x - S] : 0.f;
                float v0 = ch[x];
                float vp = rp ? ch[x + S] : 0.f;
                float elm = 0.f, el0 = 0.f, elp = 0.f, erm = 0.f, er0 = 0.f, erp = 0.f;
                if (le) { elm = rm ? ch[x - 1 - S] : 0.f; el0 = ch[x - 1]; elp = rp ? ch[x - 1 + S] : 0.f; }
                if (re) { erm = rm ? ch[x + 1 - S] : 0.f; er0 = ch[x + 1]; erp = rp ? ch[x + 1 + S] : 0.f; }
                float Lm = __shfl(vm, l - 1), L0 = __shfl(v0, l - 1), Lp = __shfl(vp, l - 1);
                float Rm = __shfl(vm, l + 1), R0 = __shfl(v0, l + 1), Rp = __shfl(vp, l + 1);
                if (lp == 0)  { Lm = elm; L0 = el0; Lp = elp; }
                if (lp == 15) { Rm = erm; R0 = er0; Rp = erp; }
                if (x == 0)     { Lm = 0.f; L0 = 0.f; Lp = 0.f; }
                if (x == S - 1) { Rm = 0.f; R0 = 0.f; Rp = 0.f; }
                v0s[cc] = v0;
                sxs[cc] = (Lm - Rm + 2.f * (L0 - R0) + Lp - Rp) * 0.125f;
                sys[cc] = (Lm + 2.f * vm + Rm - Lp - 2.f * vp - Rp) * 0.125f;
            }
            const int cpx_ = cp ^ rxw;   // cp in [0,32): XOR of bits 2-4 stays in range
            s32[p * 96 + cpx_] = (int)cvt_pk_bf16(v0s[0], v0s[1]);
            s32[p * 96 + 32 + cpx_] = (int)cvt_pk_bf16(sxs[0], sxs[1]);
            s32[p * 96 + 64 + cpx_] = (int)cvt_pk_bf16(sys[0], sys[1]);
        }
    }
    __syncthreads();

    const short* wb = dynb + (size_t)b * PT;
    const float* pf = dynf + (size_t)b * PT;
    const f32x4 z4 = {0.f, 0.f, 0.f, 0.f};
    const int sx4 = (lp & 7) << 4;       // byte-XOR for fragment reads (row = mt*16+lp)
    const char* ss_b = (const char*)s_s;
    const char* sh_cb = (const char*)s_h;
    char* sh_b = (char*)s_h;

    // skip-path accumulator, carried phase1 -> phase3
    f32x4 acc_sk[MT];
#pragma unroll
    for (int mt = 0; mt < MT; ++mt) acc_sk[mt] = z4;

    // ---- phase 1: h1 = act(w_in * s + b_in), O=128, K=192
    //      + fused: acc_sk += w_sk * s (reuses a[mt] fragments) ----
    {
        const float bi0 = pf[24576 + (w * 2) * 16 + lp];
        const float bi1 = pf[24576 + (w * 2 + 1) * 16 + lp];
        f32x4 acc[2][MT];
#pragma unroll
        for (int n = 0; n < 2; ++n)
#pragma unroll
            for (int mt = 0; mt < MT; ++mt) acc[n][mt] = z4;
        const int osk = w * 16 + lp;
#pragma unroll 2
        for (int k = 0; k < 6; ++k) {
            bf16x8 a[MT];
#pragma unroll
            for (int mt = 0; mt < MT; ++mt)
                a[mt] = *(const bf16x8*)(ss_b + (mt * 16 + lp) * 384 + ((k * 64 + lq * 16) ^ sx4));
#pragma unroll
            for (int n = 0; n < 2; ++n) {
                int o = (w * 2 + n) * 16 + lp;
                bf16x8 bb = *(const bf16x8*)&wb[o * 192 + k * 32 + lq * 8];
#pragma unroll
                for (int mt = 0; mt < MT; ++mt)
                    acc[n][mt] = __builtin_amdgcn_mfma_f32_16x16x32_bf16(a[mt], bb, acc[n][mt], 0, 0, 0);
            }
            {
                bf16x8 bsk = *(const bf16x8*)&wb[49472 + osk * 192 + k * 32 + lq * 8];
#pragma unroll
                for (int mt = 0; mt < MT; ++mt)
                    acc_sk[mt] = __builtin_amdgcn_mfma_f32_16x16x32_bf16(a[mt], bsk, acc_sk[mt], 0, 0, 0);
            }
        }
#pragma unroll
        for (int n = 0; n < 2; ++n) {
            int o = (w * 2 + n) * 16 + lp;
            float bi = n ? bi1 : bi0;
#pragma unroll
            for (int mt = 0; mt < MT; ++mt)
#pragma unroll
                for (int r = 0; r < 4; ++r) {
                    int row = mt * 16 + lq * 4 + r;
                    *(short*)(sh_b + row * 256 + ((o * 2) ^ ((row & 7) << 4))) =
                        f2bf1(lrelu(acc[n][mt][r] + bi));
                }
        }
    }
    __syncthreads();

    // ---- phase 2: h2 = act(w_mid * h1 + b_mid)   O=128, K=128 (in-place via regs) ----
    {
        const float bi0 = pf[41088 + (w * 2) * 16 + lp];
        const float bi1 = pf[41088 + (w * 2 + 1) * 16 + lp];
        f32x4 acc[2][MT];
#pragma unroll
        for (int n = 0; n < 2; ++n)
#pragma unroll
            for (int mt = 0; mt < MT; ++mt) acc[n][mt] = z4;
#pragma unroll 2
        for (int k = 0; k < 4; ++k) {
            bf16x8 a[MT];
#pragma unroll
            for (int mt = 0; mt < MT; ++mt)
                a[mt] = *(const bf16x8*)(sh_cb + (mt * 16 + lp) * 256 + ((k * 64 + lq * 16) ^ sx4));
#pragma unroll
            for (int n = 0; n < 2; ++n) {
                int o = (w * 2 + n) * 16 + lp;
                bf16x8 bb = *(const bf16x8*)&wb[24704 + o * 128 + k * 32 + lq * 8];
#pragma unroll
                for (int mt = 0; mt < MT; ++mt)
                    acc[n][mt] = __builtin_amdgcn_mfma_f32_16x16x32_bf16(a[mt], bb, acc[n][mt], 0, 0, 0);
            }
        }
        __syncthreads();  // all h1 reads complete before overwrite
#pragma unroll
        for (int n = 0; n < 2; ++n) {
            int o = (w * 2 + n) * 16 + lp;
            float bi = n ? bi1 : bi0;
#pragma unroll
            for (int mt = 0; mt < MT; ++mt)
#pragma unroll
                for (int r = 0; r < 4; ++r) {
                    int row = mt * 16 + lq * 4 + r;
                    *(short*)(sh_b + row * 256 + ((o * 2) ^ ((row & 7) << 4))) =
                        f2bf1(lrelu(acc[n][mt][r] + bi));
                }
        }
    }
    __syncthreads();

    // ---- phase 3: d = w_out*h2 + acc_sk + (b_out + b_sk)   O=64, K=128 ----
    {
        int o = w * 16 + lp;
        const float bi = pf[49408 + o] + pf[61760 + o];
        f32x4 acc[MT];
#pragma unroll
        for (int mt = 0; mt < MT; ++mt) acc[mt] = acc_sk[mt];
#pragma unroll 2
        for (int k = 0; k < 4; ++k) {
            bf16x8 bb = *(const bf16x8*)&wb[41216 + o * 128 + k * 32 + lq * 8];
#pragma unroll
            for (int mt = 0; mt < MT; ++mt) {
                bf16x8 a = *(const bf16x8*)(sh_cb + (mt * 16 + lp) * 256 + ((k * 64 + lq * 16) ^ sx4));
                acc[mt] = __builtin_amdgcn_mfma_f32_16x16x32_bf16(a, bb, acc[mt], 0, 0, 0);
            }
        }
        // no barrier needed: s_s (aliased by s_y) last read in phase 1,
        // two barriers ago; s_y writes don't touch s_h.
#pragma unroll
        for (int mt = 0; mt < MT; ++mt) {
            f32x4 dv;
#pragma unroll
            for (int r = 0; r < 4; ++r) dv[r] = acc[mt][r] + bi;
            *(f32x4*)&s_y[o * SY + mt * 16 + lq * 4] = dv;   // 16B-aligned, bank-uniform
        }
    }
    __syncthreads();

    // ---- phase 4: y = cur + leak * d  (coalesced fp32) ----
    {
        if (MT == 4) {
#pragma unroll
            for (int v = 0; v < 4; ++v) {
                int idx = v * 1024 + t * 4;
                int o = idx >> 6, px = idx & 63;
                f32x4 sv = *(const f32x4*)&s_y[o * SY + px];
                const float* cb = cur + ((size_t)b * 64 + o) * HW + pix0 + px;
                float* yb = y + ((size_t)b * 64 + o) * HW + pix0 + px;
                f32x4 cv = *(const f32x4*)cb;
                *(f32x4*)yb = cv + lk * sv;
            }
        } else {
            int o = t >> 2, px = (t & 3) * 4;
            f32x4 sv = *(const f32x4*)&s_y[o * SY + px];
            const float* cb = cur + ((size_t)b * 64 + o) * HW + pix0 + px;
            float* yb = y + ((size_t)b * 64 + o) * HW + pix0 + px;
            f32x4 cv = *(const f32x4*)cb;
            *(f32x4*)yb = cv + lk * sv;
        }
    }
}

// ---------------------------------------------------------------------------
// Kernel 4: downsample = separable 4-tap stride-2 (exact), XCD-chunked.
// ---------------------------------------------------------------------------
__global__ __launch_bounds__(256) void down_kernel(
    const float* __restrict__ yin, float* __restrict__ outp,
    int S, int S2, int TW, int CPB, int tiles)
{
    __shared__ float s_in[3072];   // [CPB][IH][IWP]
    __shared__ float s_hb[1152];   // [CPB][IH][TW+1]

    const float ga = 0.60653065971263342f;
    const float gs = 1.f / ((1.f + 2.f * ga) * (1.f + 2.f * ga));
    const float u0 = ga, u1 = 1.f + ga;

    const int t = threadIdx.x;
    const int nwg = (int)gridDim.x;          // always divisible by 8
    const int rb = (int)blockIdx.x;
    const int bi = (rb & 7) * (nwg >> 3) + (rb >> 3);
    const int tix = bi % tiles;
    const int rem = bi / tiles;
    const int tiy = rem % tiles;
    const int cg = rem / tiles;          // channel-group index
    const int bc0 = cg * CPB;            // first (b*64+c) channel

    const int IH = 2 * TW + 2;           // input rows needed
    const int IW = IH;                   // input cols needed
    const int IWP = IW + 2;              // padded LDS stride
    const int HS = TW + 1;               // h-buffer stride
    const int gy0 = tiy * 2 * TW - 1;
    const int gx0 = tix * 2 * TW - 1;

    // load input region (zero-padded), coalesced over ix
    const int loadTot = CPB * IH * IW;
    for (int j = t; j < loadTot; j += 256) {
        int c = j / (IH * IW);
        int r = j - c * (IH * IW);
        int iy = r / IW, ix = r - iy * IW;
        int gy = gy0 + iy, gx = gx0 + ix;
        float v = 0.f;
        if (gy >= 0 && gy < S && gx >= 0 && gx < S)
            v = yin[(size_t)(bc0 + c) * S * S + gy * S + gx];
        s_in[(c * IH + iy) * IWP + ix] = v;
    }
    __syncthreads();

    // horizontal 4-tap at stride 2
    const int hTot = CPB * IH * TW;
    for (int j = t; j < hTot; j += 256) {
        int c = j / (IH * TW);
        int r = j - c * (IH * TW);
        int iy = r / TW, ox = r - iy * TW;
        const float* pin = &s_in[(c * IH + iy) * IWP + 2 * ox];
        s_hb[(c * IH + iy) * HS + ox] =
            u0 * (pin[0] + pin[3]) + u1 * (pin[1] + pin[2]);
    }
    __syncthreads();

    // vertical 4-tap at stride 2 + scale; CPB*TW*TW == 256 exactly
    {
        int ox = t % TW;
        int r = t / TW;
        int oy = r % TW;
        int c = r / TW;
        const float* ph = &s_hb[(c * IH + 2 * oy) * HS + ox];
        float acc = u0 * (ph[0] + ph[3 * HS]) + u1 * (ph[HS] + ph[2 * HS]);
        outp[(size_t)(bc0 + c) * S2 * S2 + (tiy * TW + oy) * S2 + tix * TW + ox] =
            acc * 0.25f * gs;
    }
}

// ---------------------------------------------------------------------------
// Head pipeline (unchanged)
// ---------------------------------------------------------------------------
__global__ __launch_bounds__(256) void head_a_kernel(
    const float* __restrict__ emb6,
    const float* __restrict__ w0, const float* __restrict__ b0,
    const float* __restrict__ w1, const float* __restrict__ b1,
    float* __restrict__ h)
{
    __shared__ float sm_t[256], sm_v[256], sm_r[256];
    int b = blockIdx.x, t = threadIdx.x;
    sm_t[t] = emb6[b * 256 + t];
    __syncthreads();
    {
        int o = t & 63, p = t >> 6;
        float acc = 0.f;
        for (int k = 0; k < 64; ++k) acc += w0[o * 64 + k] * lrelu(sm_t[k * 4 + p]);
        sm_v[o * 4 + p] = lrelu(acc + b0[o]);
    }
    __syncthreads();
    {
        int o = t & 63, p = t >> 6;
        float acc = 0.f;
        for (int k = 0; k < 64; ++k) acc += w1[o * 64 + k] * sm_v[k * 4 + p];
        sm_r[o * 4 + p] = sm_t[o * 4 + p] + 0.1f * (acc + b1[o]);
    }
    __syncthreads();
    if (t < 64)
        h[b * 64 + t] = 0.25f * (sm_r[t * 4] + sm_r[t * 4 + 1] + sm_r[t * 4 + 2] + sm_r[t * 4 + 3]);
}

__global__ __launch_bounds__(256) void head_b_kernel(
    const float* __restrict__ h, const float* __restrict__ w,
    const float* __restrict__ bias, float* __restrict__ t1)
{
    __shared__ float s_h[64];
    int id = blockIdx.x * 256 + threadIdx.x;
    int b = id >> 10, o = id & 1023;
    if (threadIdx.x < 64) s_h[threadIdx.x] = lrelu(h[b * 64 + threadIdx.x]);
    __syncthreads();
    float acc = 0.f;
    for (int k = 0; k < 64; ++k) acc += s_h[k] * w[k * 1024 + o];
    t1[b * 1024 + o] = lrelu(acc + bias[o]);
}

__global__ __launch_bounds__(256) void head_c_kernel(
    const float* __restrict__ h, const float* __restrict__ t1,
    const float* __restrict__ sw, const float* __restrict__ sb,
    const float* __restrict__ w2, const float* __restrict__ b2,
    float* __restrict__ h1)
{
    __shared__ float s_t[8 * 128];
    __shared__ float s_h[8 * 64];
    int oblk = blockIdx.x & 1, chunk = blockIdx.x >> 1;
    int t = threadIdx.x;
    int o = oblk * 256 + t;
    for (int j = t; j < 1024; j += 256) {
        int b = j >> 7, kk = j & 127;
        s_t[j] = t1[b * 1024 + chunk * 128 + kk];
    }
    if (chunk == 0)
        for (int j = t; j < 512; j += 256) s_h[j] = h[j];
    __syncthreads();
    float acc[8];
#pragma unroll
    for (int b = 0; b < 8; ++b) acc[b] = 0.f;
    for (int kk = 0; kk < 128; ++kk) {
        float wv = w2[(chunk * 128 + kk) * 512 + o];
#pragma unroll
        for (int b = 0; b < 8; ++b) acc[b] += s_t[b * 128 + kk] * wv;
    }
#pragma unroll
    for (int b = 0; b < 8; ++b) acc[b] *= 0.1f;
    if (chunk == 0) {
        for (int k = 0; k < 64; ++k) {
            float wv = sw[k * 512 + o];
#pragma unroll
            for (int b = 0; b < 8; ++b) acc[b] += s_h[b * 64 + k] * wv;
        }
        float c0 = sb[o] + 0.1f * b2[o];
#pragma unroll
        for (int b = 0; b < 8; ++b) acc[b] += c0;
    }
#pragma unroll
    for (int b = 0; b < 8; ++b) atomicAdd(&h1[b * 512 + o], acc[b]);
}

__global__ __launch_bounds__(256) void head_d_kernel(
    const float* __restrict__ h1, const float* __restrict__ w,
    const float* __restrict__ bias, float* __restrict__ z3)
{
    __shared__ float s_u[8 * 64];
    int oblk = blockIdx.x & 1, chunk = blockIdx.x >> 1;
    int t = threadIdx.x;
    int o = oblk * 256 + t;
    for (int j = t; j < 512; j += 256) {
        int b = j >> 6, kk = j & 63;
        s_u[j] = lrelu(h1[b * 512 + chunk * 64 + kk]);
    }
    __syncthreads();
    float acc[8];
#pragma unroll
    for (int b = 0; b < 8; ++b) acc[b] = 0.f;
    for (int kk = 0; kk < 64; ++kk) {
        float wv = w[(chunk * 64 + kk) * 512 + o];
#pragma unroll
        for (int b = 0; b < 8; ++b) acc[b] += s_u[b * 64 + kk] * wv;
    }
    if (chunk == 0) {
        float c0 = bias[o];
#pragma unroll
        for (int b = 0; b < 8; ++b) acc[b] += c0;
    }
#pragma unroll
    for (int b = 0; b < 8; ++b) atomicAdd(&z3[b * 512 + o], acc[b]);
}

__global__ __launch_bounds__(256) void head_e_kernel(
    const float* __restrict__ h1, const float* __restrict__ z3,
    const float* __restrict__ w, const float* __restrict__ bias,
    float* __restrict__ h2)
{
    __shared__ float s_u[8 * 64];
    int oblk = blockIdx.x & 1, chunk = blockIdx.x >> 1;
    int t = threadIdx.x;
    int o = oblk * 256 + t;
    for (int j = t; j < 512; j += 256) {
        int b = j >> 6, kk = j & 63;
        s_u[j] = lrelu(z3[b * 512 + chunk * 64 + kk]);
    }
    __syncthreads();
    float acc[8];
#pragma unroll
    for (int b = 0; b < 8; ++b) acc[b] = 0.f;
    for (int kk = 0; kk < 64; ++kk) {
        float wv = w[(chunk * 64 + kk) * 512 + o];
#pragma unroll
        for (int b = 0; b < 8; ++b) acc[b] += s_u[b * 64 + kk] * wv;
    }
#pragma unroll
    for (int b = 0; b < 8; ++b) acc[b] *= 0.1f;
    if (chunk == 0) {
        float c0 = 0.1f * bias[o];
#pragma unroll
        for (int b = 0; b < 8; ++b) acc[b] += h1[b * 512 + o] + c0;
    }
#pragma unroll
    for (int b = 0; b < 8; ++b) atomicAdd(&h2[b * 512 + o], acc[b]);
}

__global__ __launch_bounds__(256) void head_f_kernel(
    const float* __restrict__ h2, const float* __restrict__ w,
    const float* __restrict__ bias, float* __restrict__ lat)
{
    __shared__ float s_u[8 * 64];
    int oblk = blockIdx.x & 1, chunk = blockIdx.x >> 1;
    int t = threadIdx.x;
    int o = oblk * 256 + t;
    for (int j = t; j < 512; j += 256) {
        int b = j >> 6, kk = j & 63;
        s_u[j] = h2[b * 512 + chunk * 64 + kk];
    }
    __syncthreads();
    float acc[8];
#pragma unroll
    for (int b = 0; b < 8; ++b) acc[b] = 0.f;
    for (int kk = 0; kk < 64; ++kk) {
        float wv = w[(chunk * 64 + kk) * 512 + o];
#pragma unroll
        for (int b = 0; b < 8; ++b) acc[b] += s_u[b * 64 + kk] * wv;
    }
    if (chunk == 0) {
        float c0 = bias[o];
#pragma unroll
        for (int b = 0; b < 8; ++b) acc[b] += c0;
    }
#pragma unroll
    for (int b = 0; b < 8; ++b) atomicAdd(&lat[b * 512 + o], acc[b]);
}

// ---------------------------------------------------------------------------
extern "C" void kernel_launch(void* const* d_in, const int* in_sizes, int n_in,
                              void* d_out, int out_size, void* d_ws, size_t ws_size,
                              hipStream_t stream) {
    const float* x      = (const float*)d_in[0];
    const float* inj    = (const float*)d_in[1];
    const float* leak   = (const float*)d_in[2];
    const float* in_w   = (const float*)d_in[3];
    const float* in_b   = (const float*)d_in[4];
    const float* inrb_w0 = (const float*)d_in[5];
    const float* inrb_b0 = (const float*)d_in[6];
    const float* inrb_w1 = (const float*)d_in[7];
    const float* inrb_b1 = (const float*)d_in[8];
    const float* hyp_w  = (const float*)d_in[9];
    const float* hyp_b  = (const float*)d_in[10];
    const float* outrb_w0 = (const float*)d_in[11];
    const float* outrb_b0 = (const float*)d_in[12];
    const float* outrb_w1 = (const float*)d_in[13];
    const float* outrb_b1 = (const float*)d_in[14];
    const float* l1_sw  = (const float*)d_in[15];
    const float* l1_sb  = (const float*)d_in[16];
    const float* l1_w1  = (const float*)d_in[17];
    const float* l1_b1  = (const float*)d_in[18];
    const float* l1_w2  = (const float*)d_in[19];
    const float* l1_b2  = (const float*)d_in[20];
    const float* l2_w1  = (const float*)d_in[21];
    const float* l2_b1  = (const float*)d_in[22];
    const float* l2_w2  = (const float*)d_in[23];
    const float* l2_b2  = (const float*)d_in[24];
    const float* lo_w   = (const float*)d_in[25];
    const float* lo_b   = (const float*)d_in[26];

    float* out = (float*)d_out;
    float* dyn = (float*)d_ws;
    float* ybuf = dyn + (size_t)BATCH * PT;
    short* dyn16 = (short*)(ybuf + (size_t)BATCH * 64 * 16384);
    float* hbuf = (float*)(dyn16 + (size_t)BATCH * PT);
    float* t1buf = hbuf + 512;
    float* h1buf = t1buf + 8192;
    float* z3buf = h1buf + 4096;
    float* h2buf = z3buf + 4096;

    hipMemsetAsync(h1buf, 0, (4096 * 3) * sizeof(float), stream);
    hipMemsetAsync(out, 0, 4096 * sizeof(float), stream);

    hyper_kernel<<<PT / 64, 256, 0, stream>>>(inj, hyp_w, hyp_b, dyn, dyn16);

    size_t cur = 4096;
    stem_kernel<<<BATCH * 256, 256, 0, stream>>>(
        x, in_w, in_b, inrb_w0, inrb_b0, inrb_w1, inrb_b1, out + cur);

    int S = 128, sh = 7;
    for (int i = 0; i < 6; ++i) {
        if (S >= 64) {
            iter_kernel<4><<<BATCH * (S * S / 64), 256, 0, stream>>>(
                out + cur, dyn, dyn16, leak, ybuf, S, sh);
        } else {
            iter_kernel<1><<<BATCH * (S * S / 16), 256, 0, stream>>>(
                out + cur, dyn, dyn16, leak, ybuf, S, sh);
        }
        int S2 = S >> 1;
        size_t nxt = cur + (size_t)BATCH * 64 * S * S;
        int TW = (S2 >= 16) ? 16 : S2;
        int tiles = S2 / TW;
        int CPB = 256 / (TW * TW);
        if (CPB < 1) CPB = 1;
        int grid = (BATCH * 64 / CPB) * tiles * tiles;
        down_kernel<<<grid, 256, 0, stream>>>(ybuf, out + nxt, S, S2, TW, CPB, tiles);
        cur = nxt;
        S = S2; sh -= 1;
    }

    head_a_kernel<<<BATCH, 256, 0, stream>>>(
        out + cur, outrb_w0, outrb_b0, outrb_w1, outrb_b1, hbuf);
    head_b_kernel<<<32, 256, 0, stream>>>(hbuf, l1_w1, l1_b1, t1buf);
    head_c_kernel<<<16, 256, 0, stream>>>(hbuf, t1buf, l1_sw, l1_sb, l1_w2, l1_b2, h1buf);
    head_d_kernel<<<16, 256, 0, stream>>>(h1buf, l2_w1, l2_b1, z3buf);
    head_e_kernel<<<16, 256, 0, stream>>>(h1buf, z3buf, l2_w2, l2_b2, h2buf);
    head_f_kernel<<<16, 256, 0, stream>>>(h2buf, lo_w, lo_b, out);
}

// Round 6
// 505.937 us; speedup vs baseline: 1.0031x; 1.0031x over previous
//
#include <hip/hip_runtime.h>

// Shapes
// B=8, NF=64, FIN=192, FH=128, FOUT=64, LAT=512, P_TOTAL=61824
// dyn param offsets: w_in 0, b_in 24576, w_mid 24704, b_mid 41088,
//                    w_out 41216, b_out 49408, w_sk 49472, b_sk 61760

#define BATCH 8
#define PT 61824

typedef __attribute__((ext_vector_type(8))) short bf16x8;
typedef __attribute__((ext_vector_type(4))) float f32x4;

__device__ __forceinline__ float lrelu(float v) { return v > 0.f ? v : 0.2f * v; }

__device__ __forceinline__ short f2bf(float f) {
    union { float fv; unsigned u; } v; v.fv = f;
    return (short)((v.u + 0x7fffu + ((v.u >> 16) & 1u)) >> 16);  // RNE
}

// packed f32x2 -> bf16x2 (RNE), single instruction; no builtin on gfx950
__device__ __forceinline__ unsigned cvt_pk_bf16(float lo, float hi) {
    unsigned r;
    asm("v_cvt_pk_bf16_f32 %0, %1, %2" : "=v"(r) : "v"(lo), "v"(hi));
    return r;
}
// single f32 -> bf16 (RNE) in ONE instruction (low half of cvt_pk)
__device__ __forceinline__ short f2bf1(float f) {
    unsigned r;
    asm("v_cvt_pk_bf16_f32 %0, %1, %1" : "=v"(r) : "v"(f));
    return (short)r;
}

// ---------------------------------------------------------------------------
// Kernel 1: hypernetwork  dyn[b][p] = sum_k inj[b][k] * hyp_w[k][p] + hyp_b[p]
// 4-way K-split; grid 966 (~3.8/CU). fp32 dyn written only for bias ranges.
// ---------------------------------------------------------------------------
__global__ __launch_bounds__(256) void hyper_kernel(
    const float* __restrict__ inj, const float* __restrict__ hw,
    const float* __restrict__ hb, float* __restrict__ dyn,
    short* __restrict__ dyn16)
{
    __shared__ float s_l[512 * 8];        // transposed: s_l[k*8 + b]
    __shared__ float s_part[3 * 8 * 64];  // partials from kq = 1..3
    int t = threadIdx.x;
    for (int i = t; i < 4096; i += 256) {
        int b = i >> 9, k = i & 511;
        s_l[k * 8 + b] = inj[i];
    }
    __syncthreads();
    int po = t & 63, kq = t >> 6;
    int p = blockIdx.x * 64 + po;         // PT = 966*64 exactly
    float acc[8];
#pragma unroll
    for (int b = 0; b < 8; ++b) acc[b] = 0.f;
    for (int k = kq * 128; k < kq * 128 + 128; ++k) {
        float w = hw[(size_t)k * PT + p];
        float4 a0 = *(const float4*)&s_l[k * 8];
        float4 a1 = *(const float4*)&s_l[k * 8 + 4];
        acc[0] += a0.x * w; acc[1] += a0.y * w; acc[2] += a0.z * w; acc[3] += a0.w * w;
        acc[4] += a1.x * w; acc[5] += a1.y * w; acc[6] += a1.z * w; acc[7] += a1.w * w;
    }
    if (kq > 0) {
#pragma unroll
        for (int b = 0; b < 8; ++b) s_part[((kq - 1) * 8 + b) * 64 + po] = acc[b];
    }
    __syncthreads();
    if (kq == 0) {
        float bias = hb[p];
        bool isb = (p >= 24576 && p < 24704) || (p >= 41088 && p < 41216)
                || (p >= 49408 && p < 49472) || (p >= 61760);
#pragma unroll
        for (int b = 0; b < 8; ++b) {
            float v = acc[b] + s_part[b * 64 + po] + s_part[(8 + b) * 64 + po]
                    + s_part[(16 + b) * 64 + po] + bias;
            if (isb) dyn[(size_t)b * PT + p] = v;
            dyn16[(size_t)b * PT + p] = f2bf1(v);
        }
    }
}

// ---------------------------------------------------------------------------
// Kernel 2: stem (MFMA version; ~12 us.)
// ---------------------------------------------------------------------------
__global__ __launch_bounds__(256) void stem_kernel(
    const float* __restrict__ x, const float* __restrict__ in_w,
    const float* __restrict__ in_b,
    const float* __restrict__ w0, const float* __restrict__ b0,
    const float* __restrict__ w1, const float* __restrict__ b1,
    float* __restrict__ out0)
{
    const int HW = 128 * 128;
    __shared__ float s_t0[64 * 68];      // fp32 t0 [c][px] stride 68
    __shared__ short s_vh[2 * 64 * 72];  // bf16 v then h, [px][k] stride 72
    __shared__ float s_x[192];
    short* s_v = s_vh;
    short* s_h = s_vh + 64 * 72;
    float* s_y = (float*)s_vh;           // fp32 d [c][px] stride 68 (aliases v/h)

    const int b = blockIdx.x >> 8;       // 256 tiles per sample
    const int tile = blockIdx.x & 255;
    const int pix0 = tile * 64;
    const int t = threadIdx.x;
    const int l = t & 63, w = t >> 6;
    const int lp = l & 15, lq = l >> 4;

    if (t < 192) s_x[t] = x[(size_t)b * 3 * HW + (t >> 6) * HW + pix0 + (t & 63)];
    __syncthreads();

    // ---- phase A: t0 = in_b + in_w * x (fp32), v = lrelu(t0) -> bf16 ----
    for (int j = t; j < 1024; j += 256) {
        int p = j & 63, cg = j >> 6;     // cg wave-uniform -> scalar weight loads
        float x0 = s_x[p], x1 = s_x[64 + p], x2 = s_x[128 + p];
        short pk[4];
#pragma unroll
        for (int cc = 0; cc < 4; ++cc) {
            int c = cg * 4 + cc;
            float v = in_b[c] + x0 * in_w[c * 3] + x1 * in_w[c * 3 + 1]
                    + x2 * in_w[c * 3 + 2];
            s_t0[c * 68 + p] = v;
            pk[cc] = f2bf1(lrelu(v));
        }
        *(short4*)&s_v[p * 72 + cg * 4] = make_short4(pk[0], pk[1], pk[2], pk[3]);
    }
    __syncthreads();

    const int o = w * 16 + lp;
    const f32x4 z4 = {0.f, 0.f, 0.f, 0.f};

    // weight rows as bf16 fragments (w0/w1 are tiny, L2-resident across blocks)
    bf16x8 wb0[2], wb1[2];
#pragma unroll
    for (int k = 0; k < 2; ++k) {
        bf16x8 p0, p1;
#pragma unroll
        for (int e = 0; e < 8; ++e) {
            p0[e] = f2bf1(w0[o * 64 + k * 32 + lq * 8 + e]);
            p1[e] = f2bf1(w1[o * 64 + k * 32 + lq * 8 + e]);
        }
        wb0[k] = p0; wb1[k] = p1;
    }

    // ---- phase B: h = lrelu(w0 * v + b0)  O=64, K=64 ----
    {
        float bi = b0[o];
        f32x4 acc[4];
#pragma unroll
        for (int mt = 0; mt < 4; ++mt) acc[mt] = z4;
#pragma unroll
        for (int k = 0; k < 2; ++k)
#pragma unroll
            for (int mt = 0; mt < 4; ++mt) {
                bf16x8 a = *(const bf16x8*)&s_v[(mt * 16 + lp) * 72 + k * 32 + lq * 8];
                acc[mt] = __builtin_amdgcn_mfma_f32_16x16x32_bf16(a, wb0[k], acc[mt], 0, 0, 0);
            }
#pragma unroll
        for (int mt = 0; mt < 4; ++mt)
#pragma unroll
            for (int r = 0; r < 4; ++r)
                s_h[(mt * 16 + lq * 4 + r) * 72 + o] = f2bf1(lrelu(acc[mt][r] + bi));
    }
    __syncthreads();

    // ---- phase C: d = 0.1 * (w1 * h + b1)  O=64, K=64 ----
    {
        float bi = b1[o];
        f32x4 acc[4];
#pragma unroll
        for (int mt = 0; mt < 4; ++mt) acc[mt] = z4;
#pragma unroll
        for (int k = 0; k < 2; ++k)
#pragma unroll
            for (int mt = 0; mt < 4; ++mt) {
                bf16x8 a = *(const bf16x8*)&s_h[(mt * 16 + lp) * 72 + k * 32 + lq * 8];
                acc[mt] = __builtin_amdgcn_mfma_f32_16x16x32_bf16(a, wb1[k], acc[mt], 0, 0, 0);
            }
        __syncthreads();  // all s_h reads complete before aliased s_y writes
#pragma unroll
        for (int mt = 0; mt < 4; ++mt) {
            f32x4 dv;
#pragma unroll
            for (int r = 0; r < 4; ++r) dv[r] = 0.1f * (acc[mt][r] + bi);
            *(f32x4*)&s_y[o * 68 + mt * 16 + lq * 4] = dv;
        }
    }
    __syncthreads();

    // ---- phase D: out = t0 + d, coalesced f32x4 stores ----
#pragma unroll
    for (int v = 0; v < 4; ++v) {
        int idx = v * 1024 + t * 4;
        int oo = idx >> 6, px = idx & 63;
        f32x4 t0v = *(const f32x4*)&s_t0[oo * 68 + px];
        f32x4 dv = *(const f32x4*)&s_y[oo * 68 + px];
        f32x4 ov = t0v + dv;
        *(f32x4*)&out0[((size_t)b * 64 + oo) * HW + pix0 + px] = ov;
    }
}

// ---------------------------------------------------------------------------
// Kernel 3: fused iteration via MFMA.
// Round 5 (MT==4 phase 0 rewrite): the old phase 0 issued 144 VMEM
// instructions/wave (48 main + 96 masked edge loads) -- blew the vmcnt queue
// and forced a 64-VGPR serialized schedule (counters: MfmaUtil 8%, VALUBusy
// 27%, FETCH only 18 MB -> pure latency-bound). New structure:
//  (a) vertical pre-reduce a=vm+2v0+vp, d=vm-vp -> 4 shuffles/ch (was 6),
//      sx=(aL-aR)/8, sy=(dL+2d+dR)/8 (exact reassociation);
//  (b) interior 16-px-segment boundaries exchanged via LDS halo in s_h
//      (dead during phase 0) -> edge loads only for the 2 tile-outer columns;
//  (c) all 48 main loads batch-issued into register arrays before compute.
// ---------------------------------------------------------------------------
template<int MT>
__global__ __launch_bounds__(256, 4) void iter_kernel(
    const float* __restrict__ cur, const float* __restrict__ dynf,
    const short* __restrict__ dynb, const float* __restrict__ leak_p,
    float* __restrict__ y, int S, int sh)
{
    constexpr int PX = MT * 16;
    constexpr int SY = (MT == 4) ? 68 : 20;   // fp32 out stride (words)
    __shared__ short s_s[PX * 192];   // bf16 sobel [pix][192], XOR-swizzled
    __shared__ short s_h[PX * 128];   // bf16 h1/h2 [pix][128], XOR-swizzled
    float* s_y = (float*)s_s;         // fp32 d [o][px] (plain layout)

    const int HW = S * S;
    const int tilesPer = HW / PX;
    // XCD-chunked swizzle: chunk boundary == sample boundary at every S.
    const int nwg = BATCH * tilesPer;
    const int rb = (int)blockIdx.x;
    const int lb = (rb & 7) * (nwg >> 3) + (rb >> 3);
    const int b = lb / tilesPer;
    const int tile = lb - b * tilesPer;
    const int pix0 = tile * PX;
    const int t = threadIdx.x;
    const int l = t & 63, w = t >> 6;
    const int lp = l & 15, lq = l >> 4;
    const float* base = cur + (size_t)b * 64 * HW;
    const float lk = fminf(fmaxf(leak_p[0], 0.001f), 1000.f);  // hoisted off tail

    // ---- phase 0: sin_sobel ----
    if constexpr (MT == 4) {
        const int p = lp + 16 * w;            // px in tile; row is block-uniform
        const int rxw = (p & 7) << 2;         // dword-XOR for row p
        const int gpx = pix0 + p;
        const int row = gpx >> sh;
        const int x = gpx & (S - 1);
        const bool rm = (row > 0), rp = (row < S - 1);
        float* halo_a = (float*)s_h;          // 10 slots x 64 ch (s_h dead here)
        float* halo_d = halo_a + 640;
        int* s32 = (int*)s_s;

        // batch all 48 main loads (channels c = 2*(lq+4*(j>>1)) + (j&1))
        float vm[16], vv[16], vp[16];
        const float* col = base + row * S + x;
#pragma unroll
        for (int j = 0; j < 16; ++j) {
            const int c = 2 * (lq + 4 * (j >> 1)) + (j & 1);
            const float* ch = col + (size_t)c * HW;
            vm[j] = rm ? ch[-S] : 0.f;
            vv[j] = ch[0];
            vp[j] = rp ? ch[S] : 0.f;
        }
        float a[16], d[16];
#pragma unroll
        for (int j = 0; j < 16; ++j) {
            a[j] = vm[j] + 2.f * vv[j] + vp[j];
            d[j] = vm[j] - vp[j];
        }
        // outer halo columns (x0-1 -> slot 8, x0+64 -> slot 9): p==0 / p==63
        if (w == 0 || w == 3) {
            const bool left = (w == 0) && (lp == 0);
            const bool right = (w == 3) && (lp == 15);
            if (left || right) {
                const int xe = left ? x - 1 : x + 1;
                const int slot = left ? 8 : 9;
                const bool valid = (xe >= 0) && (xe < S);
                const float* ecol = base + row * S + xe;
#pragma unroll
                for (int j = 0; j < 16; ++j) {
                    const int c = 2 * (lq + 4 * (j >> 1)) + (j & 1);
                    float em = 0.f, e0 = 0.f, ep = 0.f;
                    if (valid) {
                        const float* ch = ecol + (size_t)c * HW;
                        em = rm ? ch[-S] : 0.f;
                        e0 = ch[0];
                        ep = rp ? ch[S] : 0.f;
                    }
                    halo_a[slot * 64 + c] = em + 2.f * e0 + ep;
                    halo_d[slot * 64 + c] = em - ep;
                }
            }
        }
        // interior segment boundaries: publish own a,d (slots 0..7)
        if (lp == 0 || lp == 15) {
            const int slot = 2 * w + (lp == 15 ? 1 : 0);
#pragma unroll
            for (int j = 0; j < 16; ++j) {
                const int c = 2 * (lq + 4 * (j >> 1)) + (j & 1);
                halo_a[slot * 64 + c] = a[j];
                halo_d[slot * 64 + c] = d[j];
            }
        }
        __syncthreads();
        const int slotL = (w == 0) ? 8 : 2 * (w - 1) + 1;
        const int slotR = (w == 3) ? 9 : 2 * (w + 1);
#pragma unroll
        for (int i = 0; i < 8; ++i) {
            float sx2[2], sy2[2];
#pragma unroll
            for (int cc = 0; cc < 2; ++cc) {
                const int j = 2 * i + cc;
                const int c = 2 * (lq + 4 * i) + cc;
                float aL = __shfl(a[j], l - 1), dL = __shfl(d[j], l - 1);
                float aR = __shfl(a[j], l + 1), dR = __shfl(d[j], l + 1);
                if (lp == 0)  { aL = halo_a[slotL * 64 + c]; dL = halo_d[slotL * 64 + c]; }
                if (lp == 15) { aR = halo_a[slotR * 64 + c]; dR = halo_d[slotR * 64 + c]; }
                sx2[cc] = (aL - aR) * 0.125f;
                sy2[cc] = (dL + 2.f * d[j] + dR) * 0.125f;
            }
            const int cp = lq + 4 * i;
            const int cpx_ = cp ^ rxw;
            s32[p * 96 + cpx_] = (int)cvt_pk_bf16(vv[2 * i], vv[2 * i + 1]);
            s32[p * 96 + 32 + cpx_] = (int)cvt_pk_bf16(sx2[0], sx2[1]);
            s32[p * 96 + 64 + cpx_] = (int)cvt_pk_bf16(sy2[0], sy2[1]);
        }
    } else {
        // MT==1 path (small S, tiny grids): original shuffle scheme
        const int p = lp;
        const int rxw = (p & 7) << 2;
        const int gpx = pix0 + p;
        const int row = gpx >> sh;
        const int x = gpx & (S - 1);
        const bool rm = (row > 0), rp = (row < S - 1);
        const bool le = (lp == 0) && (x > 0);
        const bool re = (lp == 15) && (x < S - 1);
        int* s32 = (int*)s_s;
#pragma unroll
        for (int i = 0; i < 2; ++i) {
            const int cp = lq + 4 * w + 16 * i;
            float v0s[2], sxs[2], sys[2];
#pragma unroll
            for (int cc = 0; cc < 2; ++cc) {
                const int c = 2 * cp + cc;
                const float* ch = base + (size_t)c * HW + row * S;
                float vm = rm ? ch[x - S] : 0.f;
                float v0 = ch[x];
                float vp = rp ? ch[x + S] : 0.f;
                float elm = 0.f, el0 = 0.f, elp = 0.f, erm = 0.f, er0 = 0.f, erp = 0.f;
                if (le) { elm = rm ? ch[x - 1 - S] : 0.f; el0 = ch[x - 1]; elp = rp ? ch[x - 1 + S] : 0.f; }
                if (re) { erm = rm ? ch[x + 1 - S] : 0.f; er0 = ch[x + 1]; erp = rp ? ch[x + 1 + S] : 0.f; }
                float Lm = __shfl(vm, l - 1), L0 = __shfl(v0, l - 1), Lp = __shfl(vp, l - 1);
                float Rm = __shfl(vm, l + 1), R0 = __shfl(v0, l + 1), Rp = __shfl(vp, l + 1);
                if (lp == 0)  { Lm = elm; L0 = el0; Lp = elp; }
                if (lp == 15) { Rm = erm; R0 = er0; Rp = erp; }
                if (x == 0)     { Lm = 0.f; L0 = 0.f; Lp = 0.f; }
                if (x == S - 1) { Rm = 0.f; R0 = 0.f; Rp = 0.f; }
                v0s[cc] = v0;
                sxs[cc] = (Lm - Rm + 2.f * (L0 - R0) + Lp - Rp) * 0.125f;
                sys[cc] = (Lm + 2.f * vm + Rm - Lp - 2.f * vp - Rp) * 0.125f;
            }
            const int cpx_ = cp ^ rxw;
            s32[p * 96 + cpx_] = (int)cvt_pk_bf16(v0s[0], v0s[1]);
            s32[p * 96 + 32 + cpx_] = (int)cvt_pk_bf16(sxs[0], sxs[1]);
            s32[p * 96 + 64 + cpx_] = (int)cvt_pk_bf16(sys[0], sys[1]);
        }
    }
    __syncthreads();

    const short* wb = dynb + (size_t)b * PT;
    const float* pf = dynf + (size_t)b * PT;
    const f32x4 z4 = {0.f, 0.f, 0.f, 0.f};
    const int sx4 = (lp & 7) << 4;       // byte-XOR for fragment reads (row = mt*16+lp)
    const char* ss_b = (const char*)s_s;
    const char* sh_cb = (const char*)s_h;
    char* sh_b = (char*)s_h;

    // skip-path accumulator, carried phase1 -> phase3
    f32x4 acc_sk[MT];
#pragma unroll
    for (int mt = 0; mt < MT; ++mt) acc_sk[mt] = z4;

    // ---- phase 1: h1 = act(w_in * s + b_in), O=128, K=192
    //      + fused: acc_sk += w_sk * s (reuses a[mt] fragments) ----
    {
        const float bi0 = pf[24576 + (w * 2) * 16 + lp];
        const float bi1 = pf[24576 + (w * 2 + 1) * 16 + lp];
        f32x4 acc[2][MT];
#pragma unroll
        for (int n = 0; n < 2; ++n)
#pragma unroll
            for (int mt = 0; mt < MT; ++mt) acc[n][mt] = z4;
        const int osk = w * 16 + lp;
        __builtin_amdgcn_s_setprio(1);
#pragma unroll 2
        for (int k = 0; k < 6; ++k) {
            bf16x8 a[MT];
#pragma unroll
            for (int mt = 0; mt < MT; ++mt)
                a[mt] = *(const bf16x8*)(ss_b + (mt * 16 + lp) * 384 + ((k * 64 + lq * 16) ^ sx4));
#pragma unroll
            for (int n = 0; n < 2; ++n) {
                int o = (w * 2 + n) * 16 + lp;
                bf16x8 bb = *(const bf16x8*)&wb[o * 192 + k * 32 + lq * 8];
#pragma unroll
                for (int mt = 0; mt < MT; ++mt)
                    acc[n][mt] = __builtin_amdgcn_mfma_f32_16x16x32_bf16(a[mt], bb, acc[n][mt], 0, 0, 0);
            }
            {
                bf16x8 bsk = *(const bf16x8*)&wb[49472 + osk * 192 + k * 32 + lq * 8];
#pragma unroll
                for (int mt = 0; mt < MT; ++mt)
                    acc_sk[mt] = __builtin_amdgcn_mfma_f32_16x16x32_bf16(a[mt], bsk, acc_sk[mt], 0, 0, 0);
            }
        }
        __builtin_amdgcn_s_setprio(0);
#pragma unroll
        for (int n = 0; n < 2; ++n) {
            int o = (w * 2 + n) * 16 + lp;
            float bi = n ? bi1 : bi0;
#pragma unroll
            for (int mt = 0; mt < MT; ++mt)
#pragma unroll
                for (int r = 0; r < 4; ++r) {
                    int row = mt * 16 + lq * 4 + r;
                    *(short*)(sh_b + row * 256 + ((o * 2) ^ ((row & 7) << 4))) =
                        f2bf1(lrelu(acc[n][mt][r] + bi));
                }
        }
    }
    __syncthreads();

    // ---- phase 2: h2 = act(w_mid * h1 + b_mid)   O=128, K=128 (in-place via regs) ----
    {
        const float bi0 = pf[41088 + (w * 2) * 16 + lp];
        const float bi1 = pf[41088 + (w * 2 + 1) * 16 + lp];
        f32x4 acc[2][MT];
#pragma unroll
        for (int n = 0; n < 2; ++n)
#pragma unroll
            for (int mt = 0; mt < MT; ++mt) acc[n][mt] = z4;
#pragma unroll 2
        for (int k = 0; k < 4; ++k) {
            bf16x8 a[MT];
#pragma unroll
            for (int mt = 0; mt < MT; ++mt)
                a[mt] = *(const bf16x8*)(sh_cb + (mt * 16 + lp) * 256 + ((k * 64 + lq * 16) ^ sx4));
#pragma unroll
            for (int n = 0; n < 2; ++n) {
                int o = (w * 2 + n) * 16 + lp;
                bf16x8 bb = *(const bf16x8*)&wb[24704 + o * 128 + k * 32 + lq * 8];
#pragma unroll
                for (int mt = 0; mt < MT; ++mt)
                    acc[n][mt] = __builtin_amdgcn_mfma_f32_16x16x32_bf16(a[mt], bb, acc[n][mt], 0, 0, 0);
            }
        }
        __syncthreads();  // all h1 reads complete before overwrite
#pragma unroll
        for (int n = 0; n < 2; ++n) {
            int o = (w * 2 + n) * 16 + lp;
            float bi = n ? bi1 : bi0;
#pragma unroll
            for (int mt = 0; mt < MT; ++mt)
#pragma unroll
                for (int r = 0; r < 4; ++r) {
                    int row = mt * 16 + lq * 4 + r;
                    *(short*)(sh_b + row * 256 + ((o * 2) ^ ((row & 7) << 4))) =
                        f2bf1(lrelu(acc[n][mt][r] + bi));
                }
        }
    }
    __syncthreads();

    // ---- phase 3: d = w_out*h2 + acc_sk + (b_out + b_sk)   O=64, K=128 ----
    {
        int o = w * 16 + lp;
        const float bi = pf[49408 + o] + pf[61760 + o];
        f32x4 acc[MT];
#pragma unroll
        for (int mt = 0; mt < MT; ++mt) acc[mt] = acc_sk[mt];
#pragma unroll 2
        for (int k = 0; k < 4; ++k) {
            bf16x8 bb = *(const bf16x8*)&wb[41216 + o * 128 + k * 32 + lq * 8];
#pragma unroll
            for (int mt = 0; mt < MT; ++mt) {
                bf16x8 a = *(const bf16x8*)(sh_cb + (mt * 16 + lp) * 256 + ((k * 64 + lq * 16) ^ sx4));
                acc[mt] = __builtin_amdgcn_mfma_f32_16x16x32_bf16(a, bb, acc[mt], 0, 0, 0);
            }
        }
        // no barrier needed: s_s (aliased by s_y) last read in phase 1,
        // two barriers ago; s_y writes don't touch s_h.
#pragma unroll
        for (int mt = 0; mt < MT; ++mt) {
            f32x4 dv;
#pragma unroll
            for (int r = 0; r < 4; ++r) dv[r] = acc[mt][r] + bi;
            *(f32x4*)&s_y[o * SY + mt * 16 + lq * 4] = dv;   // 16B-aligned, bank-uniform
        }
    }
    __syncthreads();

    // ---- phase 4: y = cur + leak * d  (coalesced fp32) ----
    {
        if (MT == 4) {
#pragma unroll
            for (int v = 0; v < 4; ++v) {
                int idx = v * 1024 + t * 4;
                int o = idx >> 6, px = idx & 63;
                f32x4 sv = *(const f32x4*)&s_y[o * SY + px];
                const float* cb = cur + ((size_t)b * 64 + o) * HW + pix0 + px;
                float* yb = y + ((size_t)b * 64 + o) * HW + pix0 + px;
                f32x4 cv = *(const f32x4*)cb;
                *(f32x4*)yb = cv + lk * sv;
            }
        } else {
            int o = t >> 2, px = (t & 3) * 4;
            f32x4 sv = *(const f32x4*)&s_y[o * SY + px];
            const float* cb = cur + ((size_t)b * 64 + o) * HW + pix0 + px;
            float* yb = y + ((size_t)b * 64 + o) * HW + pix0 + px;
            f32x4 cv = *(const f32x4*)cb;
            *(f32x4*)yb = cv + lk * sv;
        }
    }
}

// ---------------------------------------------------------------------------
// Kernel 4: downsample = separable 4-tap stride-2 (exact), XCD-chunked.
// ---------------------------------------------------------------------------
__global__ __launch_bounds__(256) void down_kernel(
    const float* __restrict__ yin, float* __restrict__ outp,
    int S, int S2, int TW, int CPB, int tiles)
{
    __shared__ float s_in[3072];   // [CPB][IH][IWP]
    __shared__ float s_hb[1152];   // [CPB][IH][TW+1]

    const float ga = 0.60653065971263342f;
    const float gs = 1.f / ((1.f + 2.f * ga) * (1.f + 2.f * ga));
    const float u0 = ga, u1 = 1.f + ga;

    const int t = threadIdx.x;
    const int nwg = (int)gridDim.x;          // always divisible by 8
    const int rb = (int)blockIdx.x;
    const int bi = (rb & 7) * (nwg >> 3) + (rb >> 3);
    const int tix = bi % tiles;
    const int rem = bi / tiles;
    const int tiy = rem % tiles;
    const int cg = rem / tiles;          // channel-group index
    const int bc0 = cg * CPB;            // first (b*64+c) channel

    const int IH = 2 * TW + 2;           // input rows needed
    const int IW = IH;                   // input cols needed
    const int IWP = IW + 2;              // padded LDS stride
    const int HS = TW + 1;               // h-buffer stride
    const int gy0 = tiy * 2 * TW - 1;
    const int gx0 = tix * 2 * TW - 1;

    // load input region (zero-padded), coalesced over ix
    const int loadTot = CPB * IH * IW;
    for (int j = t; j < loadTot; j += 256) {
        int c = j / (IH * IW);
        int r = j - c * (IH * IW);
        int iy = r / IW, ix = r - iy * IW;
        int gy = gy0 + iy, gx = gx0 + ix;
        float v = 0.f;
        if (gy >= 0 && gy < S && gx >= 0 && gx < S)
            v = yin[(size_t)(bc0 + c) * S * S + gy * S + gx];
        s_in[(c * IH + iy) * IWP + ix] = v;
    }
    __syncthreads();

    // horizontal 4-tap at stride 2
    const int hTot = CPB * IH * TW;
    for (int j = t; j < hTot; j += 256) {
        int c = j / (IH * TW);
        int r = j - c * (IH * TW);
        int iy = r / TW, ox = r - iy * TW;
        const float* pin = &s_in[(c * IH + iy) * IWP + 2 * ox];
        s_hb[(c * IH + iy) * HS + ox] =
            u0 * (pin[0] + pin[3]) + u1 * (pin[1] + pin[2]);
    }
    __syncthreads();

    // vertical 4-tap at stride 2 + scale; CPB*TW*TW == 256 exactly
    {
        int ox = t % TW;
        int r = t / TW;
        int oy = r % TW;
        int c = r / TW;
        const float* ph = &s_hb[(c * IH + 2 * oy) * HS + ox];
        float acc = u0 * (ph[0] + ph[3 * HS]) + u1 * (ph[HS] + ph[2 * HS]);
        outp[(size_t)(bc0 + c) * S2 * S2 + (tiy * TW + oy) * S2 + tix * TW + ox] =
            acc * 0.25f * gs;
    }
}

// ---------------------------------------------------------------------------
// Head pipeline (unchanged)
// ---------------------------------------------------------------------------
__global__ __launch_bounds__(256) void head_a_kernel(
    const float* __restrict__ emb6,
    const float* __restrict__ w0, const float* __restrict__ b0,
    const float* __restrict__ w1, const float* __restrict__ b1,
    float* __restrict__ h)
{
    __shared__ float sm_t[256], sm_v[256], sm_r[256];
    int b = blockIdx.x, t = threadIdx.x;
    sm_t[t] = emb6[b * 256 + t];
    __syncthreads();
    {
        int o = t & 63, p = t >> 6;
        float acc = 0.f;
        for (int k = 0; k < 64; ++k) acc += w0[o * 64 + k] * lrelu(sm_t[k * 4 + p]);
        sm_v[o * 4 + p] = lrelu(acc + b0[o]);
    }
    __syncthreads();
    {
        int o = t & 63, p = t >> 6;
        float acc = 0.f;
        for (int k = 0; k < 64; ++k) acc += w1[o * 64 + k] * sm_v[k * 4 + p];
        sm_r[o * 4 + p] = sm_t[o * 4 + p] + 0.1f * (acc + b1[o]);
    }
    __syncthreads();
    if (t < 64)
        h[b * 64 + t] = 0.25f * (sm_r[t * 4] + sm_r[t * 4 + 1] + sm_r[t * 4 + 2] + sm_r[t * 4 + 3]);
}

__global__ __launch_bounds__(256) void head_b_kernel(
    const float* __restrict__ h, const float* __restrict__ w,
    const float* __restrict__ bias, float* __restrict__ t1)
{
    __shared__ float s_h[64];
    int id = blockIdx.x * 256 + threadIdx.x;
    int b = id >> 10, o = id & 1023;
    if (threadIdx.x < 64) s_h[threadIdx.x] = lrelu(h[b * 64 + threadIdx.x]);
    __syncthreads();
    float acc = 0.f;
    for (int k = 0; k < 64; ++k) acc += s_h[k] * w[k * 1024 + o];
    t1[b * 1024 + o] = lrelu(acc + bias[o]);
}

__global__ __launch_bounds__(256) void head_c_kernel(
    const float* __restrict__ h, const float* __restrict__ t1,
    const float* __restrict__ sw, const float* __restrict__ sb,
    const float* __restrict__ w2, const float* __restrict__ b2,
    float* __restrict__ h1)
{
    __shared__ float s_t[8 * 128];
    __shared__ float s_h[8 * 64];
    int oblk = blockIdx.x & 1, chunk = blockIdx.x >> 1;
    int t = threadIdx.x;
    int o = oblk * 256 + t;
    for (int j = t; j < 1024; j += 256) {
        int b = j >> 7, kk = j & 127;
        s_t[j] = t1[b * 1024 + chunk * 128 + kk];
    }
    if (chunk == 0)
        for (int j = t; j < 512; j += 256) s_h[j] = h[j];
    __syncthreads();
    float acc[8];
#pragma unroll
    for (int b = 0; b < 8; ++b) acc[b] = 0.f;
    for (int kk = 0; kk < 128; ++kk) {
        float wv = w2[(chunk * 128 + kk) * 512 + o];
#pragma unroll
        for (int b = 0; b < 8; ++b) acc[b] += s_t[b * 128 + kk] * wv;
    }
#pragma unroll
    for (int b = 0; b < 8; ++b) acc[b] *= 0.1f;
    if (chunk == 0) {
        for (int k = 0; k < 64; ++k) {
            float wv = sw[k * 512 + o];
#pragma unroll
            for (int b = 0; b < 8; ++b) acc[b] += s_h[b * 64 + k] * wv;
        }
        float c0 = sb[o] + 0.1f * b2[o];
#pragma unroll
        for (int b = 0; b < 8; ++b) acc[b] += c0;
    }
#pragma unroll
    for (int b = 0; b < 8; ++b) atomicAdd(&h1[b * 512 + o], acc[b]);
}

__global__ __launch_bounds__(256) void head_d_kernel(
    const float* __restrict__ h1, const float* __restrict__ w,
    const float* __restrict__ bias, float* __restrict__ z3)
{
    __shared__ float s_u[8 * 64];
    int oblk = blockIdx.x & 1, chunk = blockIdx.x >> 1;
    int t = threadIdx.x;
    int o = oblk * 256 + t;
    for (int j = t; j < 512; j += 256) {
        int b = j >> 6, kk = j & 63;
        s_u[j] = lrelu(h1[b * 512 + chunk * 64 + kk]);
    }
    __syncthreads();
    float acc[8];
#pragma unroll
    for (int b = 0; b < 8; ++b) acc[b] = 0.f;
    for (int kk = 0; kk < 64; ++kk) {
        float wv = w[(chunk * 64 + kk) * 512 + o];
#pragma unroll
        for (int b = 0; b < 8; ++b) acc[b] += s_u[b * 64 + kk] * wv;
    }
    if (chunk == 0) {
        float c0 = bias[o];
#pragma unroll
        for (int b = 0; b < 8; ++b) acc[b] += c0;
    }
#pragma unroll
    for (int b = 0; b < 8; ++b) atomicAdd(&z3[b * 512 + o], acc[b]);
}

__global__ __launch_bounds__(256) void head_e_kernel(
    const float* __restrict__ h1, const float* __restrict__ z3,
    const float* __restrict__ w, const float* __restrict__ bias,
    float* __restrict__ h2)
{
    __shared__ float s_u[8 * 64];
    int oblk = blockIdx.x & 1, chunk = blockIdx.x >> 1;
    int t = threadIdx.x;
    int o = oblk * 256 + t;
    for (int j = t; j < 512; j += 256) {
        int b = j >> 6, kk = j & 63;
        s_u[j] = lrelu(z3[b * 512 + chunk * 64 + kk]);
    }
    __syncthreads();
    float acc[8];
#pragma unroll
    for (int b = 0; b < 8; ++b) acc[b] = 0.f;
    for (int kk = 0; kk < 64; ++kk) {
        float wv = w[(chunk * 64 + kk) * 512 + o];
#pragma unroll
        for (int b = 0; b < 8; ++b) acc[b] += s_u[b * 64 + kk] * wv;
    }
#pragma unroll
    for (int b = 0; b < 8; ++b) acc[b] *= 0.1f;
    if (chunk == 0) {
        float c0 = 0.1f * bias[o];
#pragma unroll
        for (int b = 0; b < 8; ++b) acc[b] += h1[b * 512 + o] + c0;
    }
#pragma unroll
    for (int b = 0; b < 8; ++b) atomicAdd(&h2[b * 512 + o], acc[b]);
}

__global__ __launch_bounds__(256) void head_f_kernel(
    const float* __restrict__ h2, const float* __restrict__ w,
    const float* __restrict__ bias, float* __restrict__ lat)
{
    __shared__ float s_u[8 * 64];
    int oblk = blockIdx.x & 1, chunk = blockIdx.x >> 1;
    int t = threadIdx.x;
    int o = oblk * 256 + t;
    for (int j = t; j < 512; j += 256) {
        int b = j >> 6, kk = j & 63;
        s_u[j] = h2[b * 512 + chunk * 64 + kk];
    }
    __syncthreads();
    float acc[8];
#pragma unroll
    for (int b = 0; b < 8; ++b) acc[b] = 0.f;
    for (int kk = 0; kk < 64; ++kk) {
        float wv = w[(chunk * 64 + kk) * 512 + o];
#pragma unroll
        for (int b = 0; b < 8; ++b) acc[b] += s_u[b * 64 + kk] * wv;
    }
    if (chunk == 0) {
        float c0 = bias[o];
#pragma unroll
        for (int b = 0; b < 8; ++b) acc[b] += c0;
    }
#pragma unroll
    for (int b = 0; b < 8; ++b) atomicAdd(&lat[b * 512 + o], acc[b]);
}

// ---------------------------------------------------------------------------
extern "C" void kernel_launch(void* const* d_in, const int* in_sizes, int n_in,
                              void* d_out, int out_size, void* d_ws, size_t ws_size,
                              hipStream_t stream) {
    const float* x      = (const float*)d_in[0];
    const float* inj    = (const float*)d_in[1];
    const float* leak   = (const float*)d_in[2];
    const float* in_w   = (const float*)d_in[3];
    const float* in_b   = (const float*)d_in[4];
    const float* inrb_w0 = (const float*)d_in[5];
    const float* inrb_b0 = (const float*)d_in[6];
    const float* inrb_w1 = (const float*)d_in[7];
    const float* inrb_b1 = (const float*)d_in[8];
    const float* hyp_w  = (const float*)d_in[9];
    const float* hyp_b  = (const float*)d_in[10];
    const float* outrb_w0 = (const float*)d_in[11];
    const float* outrb_b0 = (const float*)d_in[12];
    const float* outrb_w1 = (const float*)d_in[13];
    const float* outrb_b1 = (const float*)d_in[14];
    const float* l1_sw  = (const float*)d_in[15];
    const float* l1_sb  = (const float*)d_in[16];
    const float* l1_w1  = (const float*)d_in[17];
    const float* l1_b1  = (const float*)d_in[18];
    const float* l1_w2  = (const float*)d_in[19];
    const float* l1_b2  = (const float*)d_in[20];
    const float* l2_w1  = (const float*)d_in[21];
    const float* l2_b1  = (const float*)d_in[22];
    const float* l2_w2  = (const float*)d_in[23];
    const float* l2_b2  = (const float*)d_in[24];
    const float* lo_w   = (const float*)d_in[25];
    const float* lo_b   = (const float*)d_in[26];

    float* out = (float*)d_out;
    float* dyn = (float*)d_ws;
    float* ybuf = dyn + (size_t)BATCH * PT;
    short* dyn16 = (short*)(ybuf + (size_t)BATCH * 64 * 16384);
    float* hbuf = (float*)(dyn16 + (size_t)BATCH * PT);
    float* t1buf = hbuf + 512;
    float* h1buf = t1buf + 8192;
    float* z3buf = h1buf + 4096;
    float* h2buf = z3buf + 4096;

    hipMemsetAsync(h1buf, 0, (4096 * 3) * sizeof(float), stream);
    hipMemsetAsync(out, 0, 4096 * sizeof(float), stream);

    hyper_kernel<<<PT / 64, 256, 0, stream>>>(inj, hyp_w, hyp_b, dyn, dyn16);

    size_t cur = 4096;
    stem_kernel<<<BATCH * 256, 256, 0, stream>>>(
        x, in_w, in_b, inrb_w0, inrb_b0, inrb_w1, inrb_b1, out + cur);

    int S = 128, sh = 7;
    for (int i = 0; i < 6; ++i) {
        if (S >= 64) {
            iter_kernel<4><<<BATCH * (S * S / 64), 256, 0, stream>>>(
                out + cur, dyn, dyn16, leak, ybuf, S, sh);
        } else {
            iter_kernel<1><<<BATCH * (S * S / 16), 256, 0, stream>>>(
                out + cur, dyn, dyn16, leak, ybuf, S, sh);
        }
        int S2 = S >> 1;
        size_t nxt = cur + (size_t)BATCH * 64 * S * S;
        int TW = (S2 >= 16) ? 16 : S2;
        int tiles = S2 / TW;
        int CPB = 256 / (TW * TW);
        if (CPB < 1) CPB = 1;
        int grid = (BATCH * 64 / CPB) * tiles * tiles;
        down_kernel<<<grid, 256, 0, stream>>>(ybuf, out + nxt, S, S2, TW, CPB, tiles);
        cur = nxt;
        S = S2; sh -= 1;
    }

    head_a_kernel<<<BATCH, 256, 0, stream>>>(
        out + cur, outrb_w0, outrb_b0, outrb_w1, outrb_b1, hbuf);
    head_b_kernel<<<32, 256, 0, stream>>>(hbuf, l1_w1, l1_b1, t1buf);
    head_c_kernel<<<16, 256, 0, stream>>>(hbuf, t1buf, l1_sw, l1_sb, l1_w2, l1_b2, h1buf);
    head_d_kernel<<<16, 256, 0, stream>>>(h1buf, l2_w1, l2_b1, z3buf);
    head_e_kernel<<<16, 256, 0, stream>>>(h1buf, z3buf, l2_w2, l2_b2, h2buf);
    head_f_kernel<<<16, 256, 0, stream>>>(h2buf, lo_w, lo_b, out);
}